// Round 3
// baseline (208.112 us; speedup 1.0000x reference)
//
#include <hip/hip_runtime.h>
#include <math.h>

#define TEMP_INV 10.0f   // 1/0.1
#define EPS 1e-8f
#define B_ 256
#define P_ 32
#define N_ 512
#define D_ 256
#define K_ (P_ + N_)     // 544
#define NWAVE 16         // 1024 threads
#define ROWS_PER_WAVE (K_ / NWAVE)   // 34

__device__ __forceinline__ float wave_reduce_sum(float v) {
    #pragma unroll
    for (int m = 32; m >= 1; m >>= 1) v += __shfl_xor(v, m, 64);
    return v;
}

__device__ __forceinline__ float wave_reduce_max(float v) {
    #pragma unroll
    for (int m = 32; m >= 1; m >>= 1) v = fmaxf(v, __shfl_xor(v, m, 64));
    return v;
}

__device__ __forceinline__ float dot4(float4 a, float4 b) {
    return a.x * b.x + a.y * b.y + a.z * b.z + a.w * b.w;
}

// One block (1024 threads = 16 waves) per batch row b.
// Phase 1: each wave computes 34 sim values into LDS (anchor frag in regs).
// Phase 2: block-wide LSE + positive-sum, one atomicAdd per block.
__global__ __launch_bounds__(1024) void fused_kernel(
    const float* __restrict__ anchors,
    const float* __restrict__ positives,
    const float* __restrict__ negatives,
    float* __restrict__ out) {
    int b    = blockIdx.x;
    int tid  = threadIdx.x;
    int wid  = tid >> 6;
    int lane = tid & 63;

    __shared__ float s_sim[K_];
    __shared__ float s_red[3 * NWAVE];

    const float4* a4 = (const float4*)(anchors + (size_t)b * D_);
    float4 a = a4[lane];
    float na = sqrtf(wave_reduce_sum(dot4(a, a)));

    const float4* pos4 = (const float4*)(positives + (size_t)b * P_ * D_);
    const float4* neg4 = (const float4*)(negatives + (size_t)b * N_ * D_);

    // rows k = wid*34 .. wid*34+33, 2-row unroll for MLP
    #pragma unroll 1
    for (int i = 0; i < ROWS_PER_WAVE; i += 2) {
        int k0 = wid * ROWS_PER_WAVE + i;
        int k1 = k0 + 1;
        const float4* p0 = (k0 < P_) ? (pos4 + (size_t)k0 * 64)
                                     : (neg4 + (size_t)(k0 - P_) * 64);
        const float4* p1 = (k1 < P_) ? (pos4 + (size_t)k1 * 64)
                                     : (neg4 + (size_t)(k1 - P_) * 64);
        float4 s0 = p0[lane];
        float4 s1 = p1[lane];
        float d0 = wave_reduce_sum(dot4(a, s0));
        float q0 = wave_reduce_sum(dot4(s0, s0));
        float d1 = wave_reduce_sum(dot4(a, s1));
        float q1 = wave_reduce_sum(dot4(s1, s1));
        if (lane == 0) {
            s_sim[k0] = d0 / fmaxf(na * sqrtf(q0), EPS) * TEMP_INV;
            s_sim[k1] = d1 / fmaxf(na * sqrtf(q1), EPS) * TEMP_INV;
        }
    }
    __syncthreads();

    // Block softmax over K_=544 values (1024 threads, 1 value per thread)
    float v = (tid < K_) ? s_sim[tid] : -INFINITY;
    float wmax = wave_reduce_max(v);
    if (lane == 0) s_red[wid] = wmax;
    __syncthreads();
    float bmax = s_red[0];
    #pragma unroll
    for (int j = 1; j < NWAVE; j++) bmax = fmaxf(bmax, s_red[j]);

    float e  = (tid < K_) ? expf(v - bmax) : 0.0f;
    float ws = wave_reduce_sum(e);
    float lp = (tid < P_) ? v : 0.0f;
    float wp = wave_reduce_sum(lp);
    if (lane == 0) {
        s_red[NWAVE + wid]     = ws;
        s_red[2 * NWAVE + wid] = wp;
    }
    __syncthreads();

    if (tid == 0) {
        float bsum = 0.0f, bpos = 0.0f;
        #pragma unroll
        for (int j = 0; j < NWAVE; j++) {
            bsum += s_red[NWAVE + j];
            bpos += s_red[2 * NWAVE + j];
        }
        float lse = bmax + logf(bsum);
        float partial = ((float)P_ * lse - bpos) * (1.0f / (float)(B_ * P_));
        atomicAdd(out, partial);
    }
}

extern "C" void kernel_launch(void* const* d_in, const int* in_sizes, int n_in,
                              void* d_out, int out_size, void* d_ws, size_t ws_size,
                              hipStream_t stream) {
    const float* anchors   = (const float*)d_in[0];
    const float* positives = (const float*)d_in[1];
    const float* negatives = (const float*)d_in[2];
    float* out = (float*)d_out;

    hipMemsetAsync(out, 0, sizeof(float), stream);  // d_out is 0xAA-poisoned
    fused_kernel<<<B_, NWAVE * 64, 0, stream>>>(anchors, positives, negatives, out);
}

// Round 4
// 202.376 us; speedup vs baseline: 1.0283x; 1.0283x over previous
//
#include <hip/hip_runtime.h>
#include <math.h>

#define TEMP_INV 10.0f   // 1/0.1
#define EPS 1e-8f
#define B_ 256
#define P_ 32
#define N_ 512
#define D_ 256
#define K_ (P_ + N_)     // 544
#define G_ (K_ / 4)      // 136 groups of 4 samples per batch row

__device__ __forceinline__ float wave_reduce_sum(float v) {
    #pragma unroll
    for (int m = 32; m >= 1; m >>= 1) v += __shfl_xor(v, m, 64);
    return v;
}

__device__ __forceinline__ float wave_reduce_max(float v) {
    #pragma unroll
    for (int m = 32; m >= 1; m >>= 1) v = fmaxf(v, __shfl_xor(v, m, 64));
    return v;
}

__device__ __forceinline__ float dot4(float4 a, float4 b) {
    return a.x * b.x + a.y * b.y + a.z * b.z + a.w * b.w;
}

// One wave per (b, group-of-4-k): anchor loaded & reduced once per wave,
// 4 independent 1 KB sample loads in flight. 64 lanes x float4 = D=256.
// 8704 blocks -> ~34 blocks/CU queued: deep latency hiding, HBM-bound.
__global__ __launch_bounds__(256) void sim_kernel(
    const float* __restrict__ anchors,
    const float* __restrict__ positives,
    const float* __restrict__ negatives,
    float* __restrict__ sim,
    float* __restrict__ out) {
    int gw   = blockIdx.x * 4 + (threadIdx.x >> 6);   // 0 .. B_*G_-1 exactly
    int lane = threadIdx.x & 63;
    int b  = gw / G_;
    int g  = gw - b * G_;
    int k0 = g * 4;

    const float4* a4 = (const float4*)(anchors + (size_t)b * D_);
    float4 a = a4[lane];

    // P_=32 divisible by 4: group is entirely positive or entirely negative
    const float4* base = (k0 < P_)
        ? (const float4*)(positives + ((size_t)b * P_ + k0) * D_)
        : (const float4*)(negatives + ((size_t)b * N_ + (k0 - P_)) * D_);

    float4 s0 = base[lane];
    float4 s1 = base[64 + lane];
    float4 s2 = base[128 + lane];
    float4 s3 = base[192 + lane];

    float na = sqrtf(wave_reduce_sum(dot4(a, a)));

    float d0 = wave_reduce_sum(dot4(a, s0));
    float q0 = wave_reduce_sum(dot4(s0, s0));
    float d1 = wave_reduce_sum(dot4(a, s1));
    float q1 = wave_reduce_sum(dot4(s1, s1));
    float d2 = wave_reduce_sum(dot4(a, s2));
    float q2 = wave_reduce_sum(dot4(s2, s2));
    float d3 = wave_reduce_sum(dot4(a, s3));
    float q3 = wave_reduce_sum(dot4(s3, s3));

    if (lane == 0) {
        float* row = sim + (size_t)b * K_ + k0;
        row[0] = d0 / fmaxf(na * sqrtf(q0), EPS) * TEMP_INV;
        row[1] = d1 / fmaxf(na * sqrtf(q1), EPS) * TEMP_INV;
        row[2] = d2 / fmaxf(na * sqrtf(q2), EPS) * TEMP_INV;
        row[3] = d3 / fmaxf(na * sqrtf(q3), EPS) * TEMP_INV;
    }

    // zero the (0xAA-poisoned) scalar output before softmax's atomics;
    // stream order guarantees this kernel completes before softmax starts.
    if (blockIdx.x == 0 && threadIdx.x == 0) out[0] = 0.0f;
}

// One block (256 threads = 4 waves) per batch row b: LSE + atomic loss add.
__global__ __launch_bounds__(256) void softmax_kernel(
    const float* __restrict__ sim,
    float* __restrict__ out) {
    int b    = blockIdx.x;
    int tid  = threadIdx.x;
    int wid  = tid >> 6;
    int lane = tid & 63;
    const float* row = sim + (size_t)b * K_;

    // K_=544 -> each thread holds up to 3 values
    float vals[3];
    int cnt = 0;
    float lmax = -INFINITY;
    for (int k = tid; k < K_; k += 256) {
        float v = row[k];
        vals[cnt++] = v;
        lmax = fmaxf(lmax, v);
    }

    __shared__ float s_max[4];
    __shared__ float s_sum[4];
    __shared__ float s_pos[4];

    float wmax = wave_reduce_max(lmax);
    if (lane == 0) s_max[wid] = wmax;
    __syncthreads();
    float bmax = fmaxf(fmaxf(s_max[0], s_max[1]), fmaxf(s_max[2], s_max[3]));

    float lsum = 0.0f;
    for (int i = 0; i < cnt; i++) lsum += expf(vals[i] - bmax);
    float wsum = wave_reduce_sum(lsum);
    if (lane == 0) s_sum[wid] = wsum;

    // sum of sim over first P columns: only k = tid chunk can have k < P
    float lp = (tid < P_) ? vals[0] : 0.0f;
    float wp = wave_reduce_sum(lp);
    if (lane == 0) s_pos[wid] = wp;
    __syncthreads();

    if (tid == 0) {
        float bsum = s_sum[0] + s_sum[1] + s_sum[2] + s_sum[3];
        float bpos = s_pos[0] + s_pos[1] + s_pos[2] + s_pos[3];
        float lse  = bmax + logf(bsum);
        float partial = ((float)P_ * lse - bpos) * (1.0f / (float)(B_ * P_));
        atomicAdd(out, partial);
    }
}

extern "C" void kernel_launch(void* const* d_in, const int* in_sizes, int n_in,
                              void* d_out, int out_size, void* d_ws, size_t ws_size,
                              hipStream_t stream) {
    const float* anchors   = (const float*)d_in[0];
    const float* positives = (const float*)d_in[1];
    const float* negatives = (const float*)d_in[2];
    float* out = (float*)d_out;
    float* sim = (float*)d_ws;                      // B_*K_ floats

    int n_waves  = B_ * G_;                         // 34816, divisible by 4
    int n_blocks = n_waves / 4;                     // 8704 blocks, 4 waves each
    sim_kernel<<<n_blocks, 256, 0, stream>>>(anchors, positives, negatives, sim, out);
    softmax_kernel<<<B_, 256, 0, stream>>>(sim, out);
}